// Round 7
// baseline (369.727 us; speedup 1.0000x reference)
//
#include <hip/hip_runtime.h>
#include <hip/hip_bf16.h>
#include <math.h>

#define NB 8
#define NN 512
#define NC 256
#define HID 32
#define GD 256   // persistent grid: 256 blocks = 1/CU, co-residency guaranteed

typedef __attribute__((ext_vector_type(8))) short short8;
typedef __attribute__((ext_vector_type(4))) float float4v;
typedef unsigned short ushort_t;

__device__ __forceinline__ ushort_t f2bf(float x) {
    unsigned u = __float_as_uint(x);
    return (ushort_t)((u + 0x7fffu + ((u >> 16) & 1u)) >> 16);
}
__device__ __forceinline__ float bf2f(ushort_t h) {
    return __uint_as_float(((unsigned)h) << 16);
}

// software grid barrier: monotonic counter, one arrival per block per phase.
__device__ __forceinline__ void gbar(int* cnt, int target) {
    __syncthreads();
    if (threadIdx.x == 0) {
        __threadfence();                       // release: publish block's writes
        atomicAdd(cnt, 1);                     // device-scope by default
        while (__hip_atomic_load(cnt, __ATOMIC_RELAXED,
                                 __HIP_MEMORY_SCOPE_AGENT) < target)
            __builtin_amdgcn_s_sleep(2);
        __threadfence();                       // acquire: see others' writes
    }
    __syncthreads();
}

struct Params {
    const float *x, *A, *mask, *ew1, *eb1, *ew2, *eb2;
    const float *gw0, *gb0, *gw1, *gb1, *gw2, *gb2, *fcw, *fcb;
    float* out;
    int*   bar;
    float* xab;
    ushort_t* APh;
    ushort_t* Ahs;
    float* dsum;
    ushort_t* PTh;
    float* hA;
    float* hB;
};

union SharedT {
    struct { float sX[32][17]; float sW[32][68]; } p1;
    struct { float sI[32][65]; float sJ[32][65]; float sV[32][33]; float w2[32]; } p2;
    struct { float sH[32][17]; float sW[32][132]; ushort_t sTh[128][24]; } p3;
    struct { ushort_t sA[2][16][72]; ushort_t sPh[64][72]; float sRed[2][32][17]; } p4;
    struct { float red[4][64]; float g[64]; } p5;
};

__global__ void bar_init(int* bar) { if (threadIdx.x < 64) bar[threadIdx.x] = 0; }

__global__ __launch_bounds__(256, 1) void mega(Params P)
{
    __shared__ __align__(16) SharedT sh;
    int t = threadIdx.x;
    int bid = blockIdx.x;
    int barn = 0;

    //======== phase 1: xab = x @ [wa|wb] (+eb1 on wb half); zero dsum ========
    if (bid < 32) P.dsum[bid * 256 + t] = 0.f;
    for (int r0 = bid * 16; r0 < 4096 * 0 + (bid + 1) * 16; r0 += 16) {  // one tile
        int tx = t & 15, ty = t >> 4;
        float acc[4] = {0.f, 0.f, 0.f, 0.f};
        for (int k0 = 0; k0 < NC; k0 += 32) {
            {
                int kk = (t & 15) * 2, r = t >> 4;
                float2 v = *(const float2*)(P.x + (size_t)(r0 + r) * NC + k0 + kk);
                sh.p1.sX[kk][r] = v.x; sh.p1.sX[kk + 1][r] = v.y;
            }
            {
                int c4 = (t & 15) * 4;
                int half = c4 >> 5, cc = c4 & 31;
#pragma unroll
                for (int rr = 0; rr < 2; ++rr) {
                    int kk = (t >> 4) + rr * 16;
                    *(float4*)&sh.p1.sW[kk][c4] =
                        *(const float4*)(P.ew1 + (size_t)(half * NC + k0 + kk) * HID + cc);
                }
            }
            __syncthreads();
#pragma unroll
            for (int k = 0; k < 32; ++k) {
                float a = sh.p1.sX[k][ty];
                float4 w = *(const float4*)&sh.p1.sW[k][tx * 4];
                acc[0] = fmaf(a, w.x, acc[0]); acc[1] = fmaf(a, w.y, acc[1]);
                acc[2] = fmaf(a, w.z, acc[2]); acc[3] = fmaf(a, w.w, acc[3]);
            }
            __syncthreads();
        }
        int c4 = tx * 4;
        float4 o; o.x = acc[0]; o.y = acc[1]; o.z = acc[2]; o.w = acc[3];
        if (c4 >= 32) {
            o.x += P.eb1[c4 - 32]; o.y += P.eb1[c4 - 31];
            o.z += P.eb1[c4 - 30]; o.w += P.eb1[c4 - 29];
        }
        *(float4*)&P.xab[(size_t)(r0 + ty) * 64 + c4] = o;
    }
    gbar(P.bar, ++barn * GD);

    //======== phase 2: edge scores -> AP bf16 + degree sums + A conv ========
    for (int u = bid; u < 136 * NB; u += GD) {
        __syncthreads();
        int b = u / 136, p = u - b * 136;
        int X = 0;
        while ((X + 1) * 16 - ((X + 1) * X) / 2 <= p) ++X;
        int Y = X + (p - (X * 16 - (X * (X - 1)) / 2));
        int i0 = X * 32, j0 = Y * 32;
        if (t < 32) sh.p2.w2[t] = P.ew2[t];
        {
            int c4 = (t & 15) * 4;
#pragma unroll
            for (int rr = 0; rr < 2; ++rr) {
                int r = (t >> 4) + rr * 16;
                float4 vi = *(const float4*)(P.xab + ((size_t)(b * NN + i0 + r)) * 64 + c4);
                float4 vj = *(const float4*)(P.xab + ((size_t)(b * NN + j0 + r)) * 64 + c4);
                sh.p2.sI[r][c4] = vi.x; sh.p2.sI[r][c4 + 1] = vi.y;
                sh.p2.sI[r][c4 + 2] = vi.z; sh.p2.sI[r][c4 + 3] = vi.w;
                sh.p2.sJ[r][c4] = vj.x; sh.p2.sJ[r][c4 + 1] = vj.y;
                sh.p2.sJ[r][c4 + 2] = vj.z; sh.p2.sJ[r][c4 + 3] = vj.w;
            }
        }
        __syncthreads();
        float eb2v = P.eb2[0];
#pragma unroll
        for (int pz = 0; pz < 4; ++pz) {
            int e = t + pz * 256;
            int ti = e >> 5, tj = e & 31;
            int i = i0 + ti, j = j0 + tj;
            float sij = 0.f, sji = 0.f;
#pragma unroll
            for (int k = 0; k < 32; ++k) {
                sij = fmaf(fmaxf(sh.p2.sI[ti][k] + sh.p2.sJ[tj][32 + k], 0.f), sh.p2.w2[k], sij);
                sji = fmaf(fmaxf(sh.p2.sJ[tj][k] + sh.p2.sI[ti][32 + k], 0.f), sh.p2.w2[k], sji);
            }
            bool ok = (i != j) && (P.mask[b * NN + i] > 0.f) && (P.mask[b * NN + j] > 0.f);
            sh.p2.sV[ti][tj] = ok ? expf(0.5f * (sij + sji) + eb2v) : 0.f;
        }
        __syncthreads();
#pragma unroll
        for (int pz = 0; pz < 4; ++pz) {
            int r = (t >> 5) + pz * 8, c = t & 31;
            size_t o1 = ((size_t)(b * NN + i0 + r)) * NN + j0 + c;
            size_t o2 = ((size_t)(b * NN + j0 + r)) * NN + i0 + c;
            P.APh[o1] = f2bf(sh.p2.sV[r][c]);
            P.APh[o2] = f2bf(sh.p2.sV[c][r]);
        }
        if (t < 32) {
            float s = 0.f;
#pragma unroll
            for (int r = 0; r < 32; ++r) s += sh.p2.sV[r][t];
            atomicAdd(&P.dsum[(NB * NN) + b * NN + j0 + t], s);
        } else if (t < 64 && X != Y) {
            int c = t - 32;
            float s = 0.f;
#pragma unroll
            for (int j = 0; j < 32; ++j) s += sh.p2.sV[c][j];
            atomicAdd(&P.dsum[(NB * NN) + b * NN + i0 + c], s);
        }
        if (p < 128) {
            const float* Ar = P.A + ((size_t)b * NN + 4 * p) * NN;
            ushort_t* Hr = P.Ahs + ((size_t)b * NN + 4 * p) * NN;
            float s0 = 0.f, s1 = 0.f;
#pragma unroll
            for (int rr = 0; rr < 4; ++rr) {
                float a0 = Ar[(size_t)rr * NN + t];
                float a1 = Ar[(size_t)rr * NN + t + 256];
                Hr[(size_t)rr * NN + t] = f2bf(a0);
                Hr[(size_t)rr * NN + t + 256] = f2bf(a1);
                s0 += a0; s1 += a1;
            }
            atomicAdd(&P.dsum[b * NN + t], s0);
            atomicAdd(&P.dsum[b * NN + t + 256], s1);
        }
    }
    gbar(P.bar, ++barn * GD);

    //======== layers: pre_gemmT then fused_mfma (2 tiles/block) ========
    int lane = t & 63, w = t >> 6;
    int quad = lane >> 4, m16 = lane & 15;
    int lap = w >> 1;
    int sa_arr = t >> 7, sa_id = t & 127;
    int sa_r = sa_id >> 3, sa_q = sa_id & 7;

    for (int L = 0; L < 3; ++L) {
        const float* hsrc = (L == 0) ? P.x : ((L == 1) ? P.hA : P.hB);
        const float* gw   = (L == 0) ? P.gw0 : ((L == 1) ? P.gw1 : P.gw2);
        const float* gb   = (L == 0) ? P.gb0 : ((L == 1) ? P.gb1 : P.gb2);
        float* hout       = (L == 1) ? P.hB : P.hA;
        int Cin           = (L == 0) ? NC : 64;

        // ---- pre_gemmT: PT[b][c][i] = bf16( d * (h @ [W0|W1]) ), transposed
        {
            int r0 = bid * 16;
            int tx = t & 31, ty = t >> 5;
            float acc0[4] = {0.f, 0.f, 0.f, 0.f};
            float acc1[4] = {0.f, 0.f, 0.f, 0.f};
            for (int k0 = 0; k0 < Cin; k0 += 32) {
                __syncthreads();
                {
                    int kk = (t & 15) * 2, r = t >> 4;
                    float2 v = *(const float2*)(hsrc + (size_t)(r0 + r) * Cin + k0 + kk);
                    sh.p3.sH[kk][r] = v.x; sh.p3.sH[kk + 1][r] = v.y;
                }
                {
                    int c4 = (t & 31) * 4;
                    int half = c4 >> 6, cc = c4 & 63;
#pragma unroll
                    for (int rr = 0; rr < 4; ++rr) {
                        int kk = (t >> 5) + rr * 8;
                        *(float4*)&sh.p3.sW[kk][c4] =
                            *(const float4*)(gw + (size_t)(half * Cin + k0 + kk) * 64 + cc);
                    }
                }
                __syncthreads();
#pragma unroll
                for (int k = 0; k < 32; ++k) {
                    float a0 = sh.p3.sH[k][ty * 2];
                    float a1 = sh.p3.sH[k][ty * 2 + 1];
                    float4 ww = *(const float4*)&sh.p3.sW[k][tx * 4];
                    acc0[0] = fmaf(a0, ww.x, acc0[0]); acc0[1] = fmaf(a0, ww.y, acc0[1]);
                    acc0[2] = fmaf(a0, ww.z, acc0[2]); acc0[3] = fmaf(a0, ww.w, acc0[3]);
                    acc1[0] = fmaf(a1, ww.x, acc1[0]); acc1[1] = fmaf(a1, ww.y, acc1[1]);
                    acc1[2] = fmaf(a1, ww.z, acc1[2]); acc1[3] = fmaf(a1, ww.w, acc1[3]);
                }
            }
            __syncthreads();
            int c4 = tx * 4;
            const float* draw = P.dsum + ((c4 >= 64) ? (NB * NN) : 0);
#pragma unroll
            for (int r = 0; r < 2; ++r) {
                int rl = ty * 2 + r;
                int row = r0 + rl;
                float d = rsqrtf(draw[row] + 1.0f + 1e-5f);
                float* ap = (r == 0) ? acc0 : acc1;
#pragma unroll
                for (int n = 0; n < 4; ++n)
                    sh.p3.sTh[c4 + n][rl] = f2bf(d * ap[n]);
            }
            __syncthreads();
            {
                int c = t & 127, half = t >> 7;
                int bb = r0 >> 9, ibase = r0 & (NN - 1);
                ushort_t* dst = P.PTh + ((size_t)(bb * 128 + c)) * NN + ibase + half * 8;
                *(short8*)dst = *(const short8*)&sh.p3.sTh[c][half * 8];
            }
        }
        gbar(P.bar, ++barn * GD);

        // ---- fused dual-Laplacian MFMA GEMM + epilogue, 2 tiles per block
        for (int fu = bid; fu < 512; fu += GD) {
            int fb = fu >> 6, frem = fu & 63;
            int fch = frem >> 5, fi0 = (frem & 31) * 16;
            const ushort_t* sa_src = (sa_arr ? P.APh : P.Ahs)
                + ((size_t)(fb * NN + fi0 + sa_r)) * NN + sa_q * 8;
            float4v acc = {0.f, 0.f, 0.f, 0.f};
            for (int k0 = 0; k0 < NN; k0 += 64) {
                __syncthreads();
                *(short8*)&sh.p4.sA[sa_arr][sa_r][sa_q * 8] = *(const short8*)(sa_src + k0);
#pragma unroll
                for (int cc = 0; cc < 2; ++cc) {
                    int chunk = t + cc * 256;
                    int l = chunk >> 3, q = chunk & 7;
                    int colg = (l >> 5) * 64 + fch * 32 + (l & 31);
                    const ushort_t* src = P.PTh + ((size_t)(fb * 128 + colg)) * NN + k0 + q * 8;
                    *(short8*)&sh.p4.sPh[l][q * 8] = *(const short8*)src;
                }
                __syncthreads();
#pragma unroll
                for (int kh = 0; kh < 2; ++kh) {
                    int ko = kh * 32 + quad * 8;
                    short8 ph = *(const short8*)&sh.p4.sPh[w * 16 + m16][ko];
                    short8 av = *(const short8*)&sh.p4.sA[lap][m16][ko];
                    acc = __builtin_amdgcn_mfma_f32_16x16x32_bf16(ph, av, acc, 0, 0, 0);
                }
            }
            int gi = fb * NN + fi0 + m16;
            float d = rsqrtf(P.dsum[lap * (NB * NN) + gi] + 1.0f + 1e-5f);
            int cbase = (w & 1) * 16 + quad * 4;
            __syncthreads();
#pragma unroll
            for (int r = 0; r < 4; ++r) {
                int c32 = cbase + r;
                int pcol = lap * 64 + fch * 32 + c32;
                size_t pidx = ((size_t)(fb * 128 + pcol)) * NN + fi0 + m16;
                float pv = bf2f(P.PTh[pidx]);
                sh.p4.sRed[lap][c32][m16] = d * (acc[r] + pv);
            }
            __syncthreads();
#pragma unroll
            for (int s = 0; s < 2; ++s) {
                int idx = t + s * 256;
                int c32 = idx & 31, i = idx >> 5;
                int gi2 = fb * NN + fi0 + i;
                float v = (sh.p4.sRed[0][c32][i] + sh.p4.sRed[1][c32][i]
                           + gb[fch * 32 + c32]) * P.mask[gi2];
                hout[(size_t)gi2 * 64 + fch * 32 + c32] = fmaxf(v, 0.f);
            }
        }
        gbar(P.bar, ++barn * GD);
    }

    //======== final: max-pool over i, then g @ fcw + fcb ========
    if (bid < NB) {
        int b = bid;
        int o = t & 63, seg = t >> 6;
        const float* Hb = P.hA + (size_t)b * NN * 64;
        float mx = -INFINITY;
        for (int i = seg; i < NN; i += 4) mx = fmaxf(mx, Hb[(size_t)i * 64 + o]);
        sh.p5.red[seg][o] = mx;
        __syncthreads();
        if (seg == 0)
            sh.p5.g[o] = fmaxf(fmaxf(sh.p5.red[0][o], sh.p5.red[1][o]),
                               fmaxf(sh.p5.red[2][o], sh.p5.red[3][o]));
        __syncthreads();
        if (t < 2) {
            float acc = P.fcb[t];
            for (int k = 0; k < 64; ++k) acc = fmaf(sh.p5.g[k], P.fcw[k * 2 + t], acc);
            P.out[b * 2 + t] = acc;
        }
    }
}

extern "C" void kernel_launch(void* const* d_in, const int* in_sizes, int n_in,
                              void* d_out, int out_size, void* d_ws, size_t ws_size,
                              hipStream_t stream)
{
    char* ws = (char*)d_ws;
    const size_t NEL = (size_t)NB * NN * NN;      // 2,097,152

    Params P;
    P.x    = (const float*)d_in[0];
    P.A    = (const float*)d_in[1];
    P.mask = (const float*)d_in[2];
    P.ew1  = (const float*)d_in[3];
    P.eb1  = (const float*)d_in[4];
    P.ew2  = (const float*)d_in[5];
    P.eb2  = (const float*)d_in[6];
    P.gw0  = (const float*)d_in[7];
    P.gb0  = (const float*)d_in[8];
    P.gw1  = (const float*)d_in[9];
    P.gb1  = (const float*)d_in[10];
    P.gw2  = (const float*)d_in[11];
    P.gb2  = (const float*)d_in[12];
    P.fcw  = (const float*)d_in[13];
    P.fcb  = (const float*)d_in[14];
    P.out  = (float*)d_out;

    P.bar  = (int*)ws;                      ws += 64 * 4;
    P.xab  = (float*)ws;                    ws += 262144 * 4;
    P.APh  = (ushort_t*)ws;                 ws += NEL * 2;
    P.Ahs  = (ushort_t*)ws;                 ws += NEL * 2;
    P.dsum = (float*)ws;                    ws += 8192 * 4;
    P.PTh  = (ushort_t*)ws;                 ws += 524288 * 2;
    P.hA   = (float*)ws;                    ws += 262144 * 4;
    P.hB   = (float*)ws;                    ws += 262144 * 4;

    bar_init<<<1, 64, 0, stream>>>(P.bar);
    mega<<<GD, 256, 0, stream>>>(P);
}

// Round 8
// 197.285 us; speedup vs baseline: 1.8741x; 1.8741x over previous
//
#include <hip/hip_runtime.h>
#include <hip/hip_bf16.h>
#include <math.h>

#define NB 8
#define NN 512
#define NC 256
#define HID 32

typedef __attribute__((ext_vector_type(8))) short short8;
typedef __attribute__((ext_vector_type(4))) float float4v;
typedef unsigned short ushort_t;

__device__ __forceinline__ ushort_t f2bf(float x) {
    unsigned u = __float_as_uint(x);
    return (ushort_t)((u + 0x7fffu + ((u >> 16) & 1u)) >> 16);
}
__device__ __forceinline__ float bf2f(ushort_t h) {
    return __uint_as_float(((unsigned)h) << 16);
}

// ---------------------------------------------------------------------------
// Kernel 1: xab = x @ [wa|wb] (+eb1). Zeroes dsum (bid<32) and gmax/done (bid 32).
// ---------------------------------------------------------------------------
__global__ __launch_bounds__(256) void xaxb_gemm(
    const float* __restrict__ x, const float* __restrict__ ew1,
    const float* __restrict__ eb1, float* __restrict__ xab,
    float* __restrict__ dsum, unsigned* __restrict__ gmax, int* __restrict__ done)
{
    __shared__ float sX[32][17];
    __shared__ float sW[32][68];
    int t = threadIdx.x;
    if (blockIdx.x < 32) dsum[blockIdx.x * 256 + t] = 0.f;
    if (blockIdx.x == 32) {
        gmax[t] = 0u; gmax[t + 256] = 0u;
        if (t < NB) done[t] = 0;
    }
    int r0 = blockIdx.x * 16;
    int tx = t & 15, ty = t >> 4;
    float acc[4] = {0.f, 0.f, 0.f, 0.f};
    for (int k0 = 0; k0 < NC; k0 += 32) {
        {
            int kk = (t & 15) * 2, r = t >> 4;
            float2 v = *(const float2*)(x + (size_t)(r0 + r) * NC + k0 + kk);
            sX[kk][r] = v.x; sX[kk + 1][r] = v.y;
        }
        {
            int c4 = (t & 15) * 4;
            int half = c4 >> 5, cc = c4 & 31;
#pragma unroll
            for (int rr = 0; rr < 2; ++rr) {
                int kk = (t >> 4) + rr * 16;
                *(float4*)&sW[kk][c4] =
                    *(const float4*)(ew1 + (size_t)(half * NC + k0 + kk) * HID + cc);
            }
        }
        __syncthreads();
#pragma unroll
        for (int k = 0; k < 32; ++k) {
            float a = sX[k][ty];
            float4 w = *(const float4*)&sW[k][tx * 4];
            acc[0] = fmaf(a, w.x, acc[0]); acc[1] = fmaf(a, w.y, acc[1]);
            acc[2] = fmaf(a, w.z, acc[2]); acc[3] = fmaf(a, w.w, acc[3]);
        }
        __syncthreads();
    }
    int c4 = tx * 4;
    float4 o; o.x = acc[0]; o.y = acc[1]; o.z = acc[2]; o.w = acc[3];
    if (c4 >= 32) {
        o.x += eb1[c4 - 32]; o.y += eb1[c4 - 31];
        o.z += eb1[c4 - 30]; o.w += eb1[c4 - 29];
    }
    *(float4*)&xab[(size_t)(r0 + ty) * 64 + c4] = o;
}

// ---------------------------------------------------------------------------
// Kernel 2: edge scores -> AP bf16 + AP col sums + A->bf16 + A col sums.
// (unchanged from round 5)
// ---------------------------------------------------------------------------
__global__ __launch_bounds__(256) void edge_scores(
    const float* __restrict__ xab, const float* __restrict__ ew2,
    const float* __restrict__ eb2, const float* __restrict__ mask,
    const float* __restrict__ A, ushort_t* __restrict__ Ah,
    ushort_t* __restrict__ APh, float* __restrict__ dsum)
{
    __shared__ float sI[32][65], sJ[32][65];
    __shared__ float sV[32][33];
    __shared__ float w2[32];
    int b = blockIdx.z;
    int p = blockIdx.x;
    int X = 0;
    while ((X + 1) * 16 - ((X + 1) * X) / 2 <= p) ++X;
    int Y = X + (p - (X * 16 - (X * (X - 1)) / 2));
    int i0 = X * 32, j0 = Y * 32;
    int t = threadIdx.x;
    if (t < 32) w2[t] = ew2[t];
    {
        int c4 = (t & 15) * 4;
#pragma unroll
        for (int rr = 0; rr < 2; ++rr) {
            int r = (t >> 4) + rr * 16;
            float4 vi = *(const float4*)(xab + ((size_t)(b * NN + i0 + r)) * 64 + c4);
            float4 vj = *(const float4*)(xab + ((size_t)(b * NN + j0 + r)) * 64 + c4);
            sI[r][c4] = vi.x; sI[r][c4 + 1] = vi.y; sI[r][c4 + 2] = vi.z; sI[r][c4 + 3] = vi.w;
            sJ[r][c4] = vj.x; sJ[r][c4 + 1] = vj.y; sJ[r][c4 + 2] = vj.z; sJ[r][c4 + 3] = vj.w;
        }
    }
    __syncthreads();
    float eb2v = eb2[0];
#pragma unroll
    for (int pz = 0; pz < 4; ++pz) {
        int e = t + pz * 256;
        int ti = e >> 5, tj = e & 31;
        int i = i0 + ti, j = j0 + tj;
        float sij = 0.f, sji = 0.f;
#pragma unroll
        for (int k = 0; k < 32; ++k) {
            sij = fmaf(fmaxf(sI[ti][k] + sJ[tj][32 + k], 0.f), w2[k], sij);
            sji = fmaf(fmaxf(sJ[tj][k] + sI[ti][32 + k], 0.f), w2[k], sji);
        }
        bool ok = (i != j) && (mask[b * NN + i] > 0.f) && (mask[b * NN + j] > 0.f);
        sV[ti][tj] = ok ? expf(0.5f * (sij + sji) + eb2v) : 0.f;
    }
    __syncthreads();
#pragma unroll
    for (int pz = 0; pz < 4; ++pz) {
        int r = (t >> 5) + pz * 8, c = t & 31;
        size_t o1 = ((size_t)(b * NN + i0 + r)) * NN + j0 + c;
        size_t o2 = ((size_t)(b * NN + j0 + r)) * NN + i0 + c;
        APh[o1] = f2bf(sV[r][c]);
        APh[o2] = f2bf(sV[c][r]);
    }
    if (t < 32) {
        float s = 0.f;
#pragma unroll
        for (int r = 0; r < 32; ++r) s += sV[r][t];
        atomicAdd(&dsum[(NB * NN) + b * NN + j0 + t], s);
    } else if (t < 64 && X != Y) {
        int c = t - 32;
        float s = 0.f;
#pragma unroll
        for (int j = 0; j < 32; ++j) s += sV[c][j];
        atomicAdd(&dsum[(NB * NN) + b * NN + i0 + c], s);
    }
    if (p < 128) {
        const float* Ar = A + ((size_t)b * NN + 4 * p) * NN;
        ushort_t* Hr = Ah + ((size_t)b * NN + 4 * p) * NN;
        float s0 = 0.f, s1 = 0.f;
#pragma unroll
        for (int rr = 0; rr < 4; ++rr) {
            float a0 = Ar[(size_t)rr * NN + t];
            float a1 = Ar[(size_t)rr * NN + t + 256];
            Hr[(size_t)rr * NN + t] = f2bf(a0);
            Hr[(size_t)rr * NN + t + 256] = f2bf(a1);
            s0 += a0; s1 += a1;
        }
        atomicAdd(&dsum[b * NN + t], s0);
        atomicAdd(&dsum[b * NN + t + 256], s1);
    }
}

// ---------------------------------------------------------------------------
// Kernel 3: pre_gemmT for layer 0 (reads global x). Unchanged from round 5.
// ---------------------------------------------------------------------------
__global__ __launch_bounds__(256) void pre_gemmT(
    const float* __restrict__ h, const float* __restrict__ gw,
    const float* __restrict__ dsum, ushort_t* __restrict__ PTh, int Cin)
{
    __shared__ float sH[32][17];
    __shared__ float sW[32][132];
    __shared__ __align__(16) ushort_t sTh[128][24];
    int r0 = blockIdx.x * 16;
    int t = threadIdx.x;
    int tx = t & 31, ty = t >> 5;
    float acc0[4] = {0.f, 0.f, 0.f, 0.f};
    float acc1[4] = {0.f, 0.f, 0.f, 0.f};
    for (int k0 = 0; k0 < Cin; k0 += 32) {
        {
            int kk = (t & 15) * 2, r = t >> 4;
            float2 v = *(const float2*)(h + (size_t)(r0 + r) * Cin + k0 + kk);
            sH[kk][r] = v.x; sH[kk + 1][r] = v.y;
        }
        {
            int c4 = (t & 31) * 4;
            int half = c4 >> 6, cc = c4 & 63;
#pragma unroll
            for (int rr = 0; rr < 4; ++rr) {
                int kk = (t >> 5) + rr * 8;
                *(float4*)&sW[kk][c4] =
                    *(const float4*)(gw + (size_t)(half * Cin + k0 + kk) * 64 + cc);
            }
        }
        __syncthreads();
#pragma unroll
        for (int k = 0; k < 32; ++k) {
            float a0 = sH[k][ty * 2];
            float a1 = sH[k][ty * 2 + 1];
            float4 w = *(const float4*)&sW[k][tx * 4];
            acc0[0] = fmaf(a0, w.x, acc0[0]); acc0[1] = fmaf(a0, w.y, acc0[1]);
            acc0[2] = fmaf(a0, w.z, acc0[2]); acc0[3] = fmaf(a0, w.w, acc0[3]);
            acc1[0] = fmaf(a1, w.x, acc1[0]); acc1[1] = fmaf(a1, w.y, acc1[1]);
            acc1[2] = fmaf(a1, w.z, acc1[2]); acc1[3] = fmaf(a1, w.w, acc1[3]);
        }
        __syncthreads();
    }
    int c4 = tx * 4;
    const float* draw = dsum + ((c4 >= 64) ? (NB * NN) : 0);
#pragma unroll
    for (int r = 0; r < 2; ++r) {
        int rl = ty * 2 + r;
        int row = r0 + rl;
        float d = rsqrtf(draw[row] + 1.0f + 1e-5f);
        float* ap = (r == 0) ? acc0 : acc1;
#pragma unroll
        for (int n = 0; n < 4; ++n)
            sTh[c4 + n][rl] = f2bf(d * ap[n]);
    }
    __syncthreads();
    {
        int c = t & 127, half = t >> 7;
        int bb = r0 >> 9, ibase = r0 & (NN - 1);
        ushort_t* dst = PTh + ((size_t)(bb * 128 + c)) * NN + ibase + half * 8;
        *(short8*)dst = *(const short8*)&sTh[c][half * 8];
    }
}

// ---------------------------------------------------------------------------
// Kernel 4/5/6: fused layer. Block = 16 rows x 64 cols x 2 laps (4 waves).
//  1) dual-Laplacian MFMA GEMM from PTin -> sRed -> sH16 (=relu layer out)
//  2) mode==0: pre_gemmT(next layer) from sH16 -> PTout (double-buffered)
//     mode==1: block-local col-max -> atomicMax; last block per batch does FC.
// ---------------------------------------------------------------------------
__global__ __launch_bounds__(256) void fused_layer(
    const ushort_t* __restrict__ Ah, const ushort_t* __restrict__ APh,
    const ushort_t* __restrict__ PTin, ushort_t* __restrict__ PTout,
    const float* __restrict__ dsum, const float* __restrict__ gb,
    const float* __restrict__ mask, const float* __restrict__ gwN,
    unsigned* __restrict__ gmax, int* __restrict__ done,
    const float* __restrict__ fcw, const float* __restrict__ fcb,
    float* __restrict__ out, int mode)
{
    __shared__ union {
        struct { ushort_t sA[2][16][72]; ushort_t sPh[128][72]; } f;  // 23040 B
        struct { float sW[32][132]; ushort_t sTh[128][24]; } p;       // 23040 B
    } u;
    __shared__ float sRed[2][64][17];   // [lap][c64][row]
    __shared__ float sH16[16][68];      // layer output tile
    __shared__ int   lastFlag;

    int t = threadIdx.x;
    int fb = blockIdx.x >> 5;
    int fi0 = (blockIdx.x & 31) * 16;
    int lane = t & 63, w = t >> 6;
    int quad = lane >> 4, m16 = lane & 15;
    int lap = w >> 1, cg = w & 1;       // wave's lap, 16-col group

    // ---- phase A: dual-lap MFMA GEMM over K=512
    int sa_arr = t >> 7, sa_id = t & 127;
    int sa_r = sa_id >> 3, sa_q = sa_id & 7;
    const ushort_t* sa_src = (sa_arr ? APh : Ah)
        + ((size_t)(fb * NN + fi0 + sa_r)) * NN + sa_q * 8;
    float4v acc0 = {0.f, 0.f, 0.f, 0.f};   // ch=0 (cols 0..31)
    float4v acc1 = {0.f, 0.f, 0.f, 0.f};   // ch=1 (cols 32..63)

    for (int k0 = 0; k0 < NN; k0 += 64) {
        __syncthreads();
        *(short8*)&u.f.sA[sa_arr][sa_r][sa_q * 8] = *(const short8*)(sa_src + k0);
#pragma unroll
        for (int cc = 0; cc < 4; ++cc) {
            int chunk = t + cc * 256;                 // 1024 chunks
            int l = chunk >> 3, q = chunk & 7;        // l = PT row (lap*64+c)
            const ushort_t* src = PTin + ((size_t)(fb * 128 + l)) * NN + k0 + q * 8;
            *(short8*)&u.f.sPh[l][q * 8] = *(const short8*)src;
        }
        __syncthreads();
#pragma unroll
        for (int kh = 0; kh < 2; ++kh) {
            int ko = kh * 32 + quad * 8;
            short8 av = *(const short8*)&u.f.sA[lap][m16][ko];
            short8 p0 = *(const short8*)&u.f.sPh[lap * 64 + cg * 16 + m16][ko];
            short8 p1 = *(const short8*)&u.f.sPh[lap * 64 + 32 + cg * 16 + m16][ko];
            acc0 = __builtin_amdgcn_mfma_f32_16x16x32_bf16(p0, av, acc0, 0, 0, 0);
            acc1 = __builtin_amdgcn_mfma_f32_16x16x32_bf16(p1, av, acc1, 0, 0, 0);
        }
    }
    // write sRed = d * (acc + P_self)
    int gi = fb * NN + fi0 + m16;
    float d = rsqrtf(dsum[lap * (NB * NN) + gi] + 1.0f + 1e-5f);
    int cbase = cg * 16 + quad * 4;
    __syncthreads();
#pragma unroll
    for (int ch = 0; ch < 2; ++ch) {
        const float4v* ap = ch ? &acc1 : &acc0;
#pragma unroll
        for (int r = 0; r < 4; ++r) {
            int c64 = ch * 32 + cbase + r;
            size_t pidx = ((size_t)(fb * 128 + lap * 64 + c64)) * NN + fi0 + m16;
            sRed[lap][c64][m16] = d * ((*ap)[r] + bf2f(PTin[pidx]));
        }
    }
    __syncthreads();
    // combine laps + bias + mask + relu -> sH16
#pragma unroll
    for (int s = 0; s < 4; ++s) {
        int idx = t + s * 256;
        int c = idx & 63, r = idx >> 6;
        float mv = mask[fb * NN + fi0 + r];
        float v = (sRed[0][c][r] + sRed[1][c][r] + gb[c]) * mv;
        sH16[r][c] = fmaxf(v, 0.f);
    }
    __syncthreads();

    if (mode == 0) {
        // ---- phase B: pre_gemmT(next layer), Cin=64, h = sH16
        int tx = t & 31, ty = t >> 5;
        float b0[4] = {0.f, 0.f, 0.f, 0.f};
        float b1[4] = {0.f, 0.f, 0.f, 0.f};
        for (int k0 = 0; k0 < 64; k0 += 32) {
            __syncthreads();
            {
                int c4 = (t & 31) * 4;
                int half = c4 >> 6, cc = c4 & 63;
#pragma unroll
                for (int rr = 0; rr < 4; ++rr) {
                    int kk = (t >> 5) + rr * 8;
                    *(float4*)&u.p.sW[kk][c4] =
                        *(const float4*)(gwN + (size_t)(half * 64 + k0 + kk) * 64 + cc);
                }
            }
            __syncthreads();
#pragma unroll
            for (int k = 0; k < 32; ++k) {
                float a0 = sH16[ty * 2][k0 + k];
                float a1 = sH16[ty * 2 + 1][k0 + k];
                float4 ww = *(const float4*)&u.p.sW[k][tx * 4];
                b0[0] = fmaf(a0, ww.x, b0[0]); b0[1] = fmaf(a0, ww.y, b0[1]);
                b0[2] = fmaf(a0, ww.z, b0[2]); b0[3] = fmaf(a0, ww.w, b0[3]);
                b1[0] = fmaf(a1, ww.x, b1[0]); b1[1] = fmaf(a1, ww.y, b1[1]);
                b1[2] = fmaf(a1, ww.z, b1[2]); b1[3] = fmaf(a1, ww.w, b1[3]);
            }
        }
        __syncthreads();
        int c4 = tx * 4;
        const float* draw = dsum + ((c4 >= 64) ? (NB * NN) : 0);
#pragma unroll
        for (int r = 0; r < 2; ++r) {
            int rl = ty * 2 + r;
            float dd = rsqrtf(draw[fb * NN + fi0 + rl] + 1.0f + 1e-5f);
            float* ap = (r == 0) ? b0 : b1;
#pragma unroll
            for (int n = 0; n < 4; ++n)
                u.p.sTh[c4 + n][rl] = f2bf(dd * ap[n]);
        }
        __syncthreads();
        {
            int c = t & 127, half = t >> 7;
            ushort_t* dst = PTout + ((size_t)(fb * 128 + c)) * NN + fi0 + half * 8;
            *(short8*)dst = *(const short8*)&u.p.sTh[c][half * 8];
        }
    } else {
        // ---- phase C: final max-pool + FC (last block per batch)
        if (t < 64) {
            float mx = 0.f;
#pragma unroll
            for (int r = 0; r < 16; ++r) mx = fmaxf(mx, sH16[r][t]);
            atomicMax(&gmax[fb * 64 + t], __float_as_uint(mx));
        }
        __syncthreads();
        if (t == 0) {
            __threadfence();
            int old = atomicAdd(&done[fb], 1);
            lastFlag = (old == 31);
            __threadfence();
        }
        __syncthreads();
        if (lastFlag) {
            if (t < 64) {
                unsigned ub = __hip_atomic_load(&gmax[fb * 64 + t],
                                                __ATOMIC_RELAXED,
                                                __HIP_MEMORY_SCOPE_AGENT);
                sH16[0][t] = __uint_as_float(ub);
            }
            __syncthreads();
            if (t < 2) {
                float acc = fcb[t];
#pragma unroll
                for (int k = 0; k < 64; ++k)
                    acc = fmaf(sH16[0][k], fcw[k * 2 + t], acc);
                out[fb * 2 + t] = acc;
            }
        }
    }
}

extern "C" void kernel_launch(void* const* d_in, const int* in_sizes, int n_in,
                              void* d_out, int out_size, void* d_ws, size_t ws_size,
                              hipStream_t stream)
{
    const float* x    = (const float*)d_in[0];
    const float* A    = (const float*)d_in[1];
    const float* mask = (const float*)d_in[2];
    const float* ew1  = (const float*)d_in[3];
    const float* eb1  = (const float*)d_in[4];
    const float* ew2  = (const float*)d_in[5];
    const float* eb2  = (const float*)d_in[6];
    const float* gw0  = (const float*)d_in[7];
    const float* gb0  = (const float*)d_in[8];
    const float* gw1  = (const float*)d_in[9];
    const float* gb1  = (const float*)d_in[10];
    const float* gw2  = (const float*)d_in[11];
    const float* gb2  = (const float*)d_in[12];
    const float* fcw  = (const float*)d_in[13];
    const float* fcb  = (const float*)d_in[14];
    float* out = (float*)d_out;
    char* ws = (char*)d_ws;

    const size_t NEL = (size_t)NB * NN * NN;      // 2,097,152
    float*    xab  = (float*)ws;                   ws += 262144 * 4;
    ushort_t* APh  = (ushort_t*)ws;                ws += NEL * 2;
    ushort_t* Ahs  = (ushort_t*)ws;                ws += NEL * 2;
    float*    dsum = (float*)ws;                   ws += 8192 * 4;
    ushort_t* PT_A = (ushort_t*)ws;                ws += 524288 * 2;
    ushort_t* PT_B = (ushort_t*)ws;                ws += 524288 * 2;
    unsigned* gmax = (unsigned*)ws;                ws += 512 * 4;
    int*      done = (int*)ws;                     ws += 64 * 4;
    // total ~13.3 MB

    xaxb_gemm  <<<256, 256, 0, stream>>>(x, ew1, eb1, xab, dsum, gmax, done);
    edge_scores<<<dim3(136, 1, NB), 256, 0, stream>>>(xab, ew2, eb2, mask,
                                                      A, Ahs, APh, dsum);
    pre_gemmT  <<<256, 256, 0, stream>>>(x, gw0, dsum, PT_A, 256);

    // layer 0: fused GEMM (PT_A) + pre(next, gw1) -> PT_B
    fused_layer<<<256, 256, 0, stream>>>(Ahs, APh, PT_A, PT_B, dsum, gb0, mask,
                                         gw1, gmax, done, fcw, fcb, out, 0);
    // layer 1: fused GEMM (PT_B) + pre(next, gw2) -> PT_A
    fused_layer<<<256, 256, 0, stream>>>(Ahs, APh, PT_B, PT_A, dsum, gb1, mask,
                                         gw2, gmax, done, fcw, fcb, out, 0);
    // layer 2: fused GEMM (PT_A) + max-pool + FC
    fused_layer<<<256, 256, 0, stream>>>(Ahs, APh, PT_A, PT_B, dsum, gb2, mask,
                                         gw2, gmax, done, fcw, fcb, out, 1);
}

// Round 9
// 172.179 us; speedup vs baseline: 2.1473x; 1.1458x over previous
//
#include <hip/hip_runtime.h>
#include <hip/hip_bf16.h>
#include <math.h>

#define NB 8
#define NN 512
#define NC 256
#define HID 32

typedef __attribute__((ext_vector_type(8))) short short8;
typedef __attribute__((ext_vector_type(4))) float float4v;
typedef unsigned short ushort_t;

__device__ __forceinline__ ushort_t f2bf(float x) {
    unsigned u = __float_as_uint(x);
    return (ushort_t)((u + 0x7fffu + ((u >> 16) & 1u)) >> 16);
}
__device__ __forceinline__ float bf2f(ushort_t h) {
    return __uint_as_float(((unsigned)h) << 16);
}

// ---------------------------------------------------------------------------
// Kernel 1: xab = x @ [wa|wb] (+eb1). Zeroes dsum (bid<32), gmax/done (bid 32).
// ---------------------------------------------------------------------------
__global__ __launch_bounds__(256) void xaxb_gemm(
    const float* __restrict__ x, const float* __restrict__ ew1,
    const float* __restrict__ eb1, float* __restrict__ xab,
    float* __restrict__ dsum, unsigned* __restrict__ gmax, int* __restrict__ done)
{
    __shared__ float sX[32][17];
    __shared__ float sW[32][68];
    int t = threadIdx.x;
    if (blockIdx.x < 32) dsum[blockIdx.x * 256 + t] = 0.f;
    if (blockIdx.x == 32) {
        gmax[t] = 0u; gmax[t + 256] = 0u;
        if (t < NB) done[t] = 0;
    }
    int r0 = blockIdx.x * 16;
    int tx = t & 15, ty = t >> 4;
    float acc[4] = {0.f, 0.f, 0.f, 0.f};
    for (int k0 = 0; k0 < NC; k0 += 32) {
        {
            int kk = (t & 15) * 2, r = t >> 4;
            float2 v = *(const float2*)(x + (size_t)(r0 + r) * NC + k0 + kk);
            sX[kk][r] = v.x; sX[kk + 1][r] = v.y;
        }
        {
            int c4 = (t & 15) * 4;
            int half = c4 >> 5, cc = c4 & 31;
#pragma unroll
            for (int rr = 0; rr < 2; ++rr) {
                int kk = (t >> 4) + rr * 16;
                *(float4*)&sW[kk][c4] =
                    *(const float4*)(ew1 + (size_t)(half * NC + k0 + kk) * HID + cc);
            }
        }
        __syncthreads();
#pragma unroll
        for (int k = 0; k < 32; ++k) {
            float a = sX[k][ty];
            float4 w = *(const float4*)&sW[k][tx * 4];
            acc[0] = fmaf(a, w.x, acc[0]); acc[1] = fmaf(a, w.y, acc[1]);
            acc[2] = fmaf(a, w.z, acc[2]); acc[3] = fmaf(a, w.w, acc[3]);
        }
        __syncthreads();
    }
    int c4 = tx * 4;
    float4 o; o.x = acc[0]; o.y = acc[1]; o.z = acc[2]; o.w = acc[3];
    if (c4 >= 32) {
        o.x += eb1[c4 - 32]; o.y += eb1[c4 - 31];
        o.z += eb1[c4 - 30]; o.w += eb1[c4 - 29];
    }
    *(float4*)&xab[(size_t)(r0 + ty) * 64 + c4] = o;
}

// ---------------------------------------------------------------------------
// Kernel 2: edge scores -> AP bf16 + AP col sums + A->bf16 + A col sums.
// (verbatim from round 5)
// ---------------------------------------------------------------------------
__global__ __launch_bounds__(256) void edge_scores(
    const float* __restrict__ xab, const float* __restrict__ ew2,
    const float* __restrict__ eb2, const float* __restrict__ mask,
    const float* __restrict__ A, ushort_t* __restrict__ Ah,
    ushort_t* __restrict__ APh, float* __restrict__ dsum)
{
    __shared__ float sI[32][65], sJ[32][65];
    __shared__ float sV[32][33];
    __shared__ float w2[32];
    int b = blockIdx.z;
    int p = blockIdx.x;
    int X = 0;
    while ((X + 1) * 16 - ((X + 1) * X) / 2 <= p) ++X;
    int Y = X + (p - (X * 16 - (X * (X - 1)) / 2));
    int i0 = X * 32, j0 = Y * 32;
    int t = threadIdx.x;
    if (t < 32) w2[t] = ew2[t];
    {
        int c4 = (t & 15) * 4;
#pragma unroll
        for (int rr = 0; rr < 2; ++rr) {
            int r = (t >> 4) + rr * 16;
            float4 vi = *(const float4*)(xab + ((size_t)(b * NN + i0 + r)) * 64 + c4);
            float4 vj = *(const float4*)(xab + ((size_t)(b * NN + j0 + r)) * 64 + c4);
            sI[r][c4] = vi.x; sI[r][c4 + 1] = vi.y; sI[r][c4 + 2] = vi.z; sI[r][c4 + 3] = vi.w;
            sJ[r][c4] = vj.x; sJ[r][c4 + 1] = vj.y; sJ[r][c4 + 2] = vj.z; sJ[r][c4 + 3] = vj.w;
        }
    }
    __syncthreads();
    float eb2v = eb2[0];
#pragma unroll
    for (int pz = 0; pz < 4; ++pz) {
        int e = t + pz * 256;
        int ti = e >> 5, tj = e & 31;
        int i = i0 + ti, j = j0 + tj;
        float sij = 0.f, sji = 0.f;
#pragma unroll
        for (int k = 0; k < 32; ++k) {
            sij = fmaf(fmaxf(sI[ti][k] + sJ[tj][32 + k], 0.f), w2[k], sij);
            sji = fmaf(fmaxf(sJ[tj][k] + sI[ti][32 + k], 0.f), w2[k], sji);
        }
        bool ok = (i != j) && (mask[b * NN + i] > 0.f) && (mask[b * NN + j] > 0.f);
        sV[ti][tj] = ok ? expf(0.5f * (sij + sji) + eb2v) : 0.f;
    }
    __syncthreads();
#pragma unroll
    for (int pz = 0; pz < 4; ++pz) {
        int r = (t >> 5) + pz * 8, c = t & 31;
        size_t o1 = ((size_t)(b * NN + i0 + r)) * NN + j0 + c;
        size_t o2 = ((size_t)(b * NN + j0 + r)) * NN + i0 + c;
        APh[o1] = f2bf(sV[r][c]);
        APh[o2] = f2bf(sV[c][r]);
    }
    if (t < 32) {
        float s = 0.f;
#pragma unroll
        for (int r = 0; r < 32; ++r) s += sV[r][t];
        atomicAdd(&dsum[(NB * NN) + b * NN + j0 + t], s);
    } else if (t < 64 && X != Y) {
        int c = t - 32;
        float s = 0.f;
#pragma unroll
        for (int j = 0; j < 32; ++j) s += sV[c][j];
        atomicAdd(&dsum[(NB * NN) + b * NN + i0 + c], s);
    }
    if (p < 128) {
        const float* Ar = A + ((size_t)b * NN + 4 * p) * NN;
        ushort_t* Hr = Ah + ((size_t)b * NN + 4 * p) * NN;
        float s0 = 0.f, s1 = 0.f;
#pragma unroll
        for (int rr = 0; rr < 4; ++rr) {
            float a0 = Ar[(size_t)rr * NN + t];
            float a1 = Ar[(size_t)rr * NN + t + 256];
            Hr[(size_t)rr * NN + t] = f2bf(a0);
            Hr[(size_t)rr * NN + t + 256] = f2bf(a1);
            s0 += a0; s1 += a1;
        }
        atomicAdd(&dsum[b * NN + t], s0);
        atomicAdd(&dsum[b * NN + t + 256], s1);
    }
}

// ---------------------------------------------------------------------------
// Kernel 3: pre_gemmT layer 0 (x, Cin=256) -> PT_A bf16 [b][128][512].
// (verbatim from round 5)
// ---------------------------------------------------------------------------
__global__ __launch_bounds__(256) void pre_gemmT(
    const float* __restrict__ h, const float* __restrict__ gw,
    const float* __restrict__ dsum, ushort_t* __restrict__ PTh, int Cin)
{
    __shared__ float sH[32][17];
    __shared__ float sW[32][132];
    __shared__ __align__(16) ushort_t sTh[128][24];
    int r0 = blockIdx.x * 16;
    int t = threadIdx.x;
    int tx = t & 31, ty = t >> 5;
    float acc0[4] = {0.f, 0.f, 0.f, 0.f};
    float acc1[4] = {0.f, 0.f, 0.f, 0.f};
    for (int k0 = 0; k0 < Cin; k0 += 32) {
        {
            int kk = (t & 15) * 2, r = t >> 4;
            float2 v = *(const float2*)(h + (size_t)(r0 + r) * Cin + k0 + kk);
            sH[kk][r] = v.x; sH[kk + 1][r] = v.y;
        }
        {
            int c4 = (t & 31) * 4;
            int half = c4 >> 6, cc = c4 & 63;
#pragma unroll
            for (int rr = 0; rr < 4; ++rr) {
                int kk = (t >> 5) + rr * 8;
                *(float4*)&sW[kk][c4] =
                    *(const float4*)(gw + (size_t)(half * Cin + k0 + kk) * 64 + cc);
            }
        }
        __syncthreads();
#pragma unroll
        for (int k = 0; k < 32; ++k) {
            float a0 = sH[k][ty * 2];
            float a1 = sH[k][ty * 2 + 1];
            float4 w = *(const float4*)&sW[k][tx * 4];
            acc0[0] = fmaf(a0, w.x, acc0[0]); acc0[1] = fmaf(a0, w.y, acc0[1]);
            acc0[2] = fmaf(a0, w.z, acc0[2]); acc0[3] = fmaf(a0, w.w, acc0[3]);
            acc1[0] = fmaf(a1, w.x, acc1[0]); acc1[1] = fmaf(a1, w.y, acc1[1]);
            acc1[2] = fmaf(a1, w.z, acc1[2]); acc1[3] = fmaf(a1, w.w, acc1[3]);
        }
        __syncthreads();
    }
    int c4 = tx * 4;
    const float* draw = dsum + ((c4 >= 64) ? (NB * NN) : 0);
#pragma unroll
    for (int r = 0; r < 2; ++r) {
        int rl = ty * 2 + r;
        int row = r0 + rl;
        float d = rsqrtf(draw[row] + 1.0f + 1e-5f);
        float* ap = (r == 0) ? acc0 : acc1;
#pragma unroll
        for (int n = 0; n < 4; ++n)
            sTh[c4 + n][rl] = f2bf(d * ap[n]);
    }
    __syncthreads();
    {
        int c = t & 127, half = t >> 7;
        int bb = r0 >> 9, ibase = r0 & (NN - 1);
        ushort_t* dst = PTh + ((size_t)(bb * 128 + c)) * NN + ibase + half * 8;
        *(short8*)dst = *(const short8*)&sTh[c][half * 8];
    }
}

// ---------------------------------------------------------------------------
// Kernel 4/5/6: fused layer, grid (32, 2, NB) = 512 blocks (2/CU).
// Phase A: dual-Laplacian MFMA GEMM from P (1 or 2 slices) -> h tile in LDS.
// Phase B (mode 0): partial pre-GEMM for next layer via MFMA; block's 32
//   h-cols contribute a K=32 partial, written to its ch slice (no atomics).
// Phase C (mode 1): col-max -> atomicMax; last of 64 blocks/batch does FC.
// ---------------------------------------------------------------------------
__global__ __launch_bounds__(256) void fused_layer(
    const ushort_t* __restrict__ Ah, const ushort_t* __restrict__ APh,
    const ushort_t* __restrict__ Pa, const ushort_t* __restrict__ Pb,
    ushort_t* __restrict__ Qa, ushort_t* __restrict__ Qb,
    const float* __restrict__ dsum, const float* __restrict__ gb,
    const float* __restrict__ mask, const float* __restrict__ gwN,
    unsigned* __restrict__ gmax, int* __restrict__ done,
    const float* __restrict__ fcw, const float* __restrict__ fcb,
    float* __restrict__ out, int dualP, int mode)
{
    __shared__ union {
        struct { ushort_t sA[2][16][72]; ushort_t sP1[64][72]; ushort_t sP2[64][72]; } a;
        struct { ushort_t sWT[128][40]; } b;    // W^T bf16 for phase B
    } u;
    __shared__ float sRed[2][32][17];
    __shared__ float sH16[16][36];
    __shared__ float sD[2][16];
    __shared__ int lastFlag;

    int t = threadIdx.x;
    int b = blockIdx.z, ch = blockIdx.y, i0 = blockIdx.x * 16;
    int lane = t & 63, w = t >> 6;
    int quad = lane >> 4, m16 = lane & 15;
    int lap = w >> 1, cg = w & 1;

    // ---- phase A: dual-lap MFMA GEMM over K=512 (r5 structure)
    int sa_arr = t >> 7, sa_id = t & 127;
    int sa_r = sa_id >> 3, sa_q = sa_id & 7;
    const ushort_t* sa_src = (sa_arr ? APh : Ah)
        + ((size_t)(b * NN + i0 + sa_r)) * NN + sa_q * 8;
    float4v acc = {0.f, 0.f, 0.f, 0.f};

    for (int k0 = 0; k0 < NN; k0 += 64) {
        __syncthreads();
        *(short8*)&u.a.sA[sa_arr][sa_r][sa_q * 8] = *(const short8*)(sa_src + k0);
#pragma unroll
        for (int cc2 = 0; cc2 < 2; ++cc2) {
            int chunk = t + cc2 * 256;
            int l = chunk >> 3, q = chunk & 7;
            int colg = (l >> 5) * 64 + ch * 32 + (l & 31);
            size_t off = ((size_t)(b * 128 + colg)) * NN + k0 + q * 8;
            *(short8*)&u.a.sP1[l][q * 8] = *(const short8*)(Pa + off);
            if (dualP)
                *(short8*)&u.a.sP2[l][q * 8] = *(const short8*)(Pb + off);
        }
        __syncthreads();
#pragma unroll
        for (int kh = 0; kh < 2; ++kh) {
            int ko = kh * 32 + quad * 8;
            short8 av = *(const short8*)&u.a.sA[lap][m16][ko];
            short8 p1 = *(const short8*)&u.a.sP1[w * 16 + m16][ko];
            acc = __builtin_amdgcn_mfma_f32_16x16x32_bf16(p1, av, acc, 0, 0, 0);
            if (dualP) {
                short8 p2 = *(const short8*)&u.a.sP2[w * 16 + m16][ko];
                acc = __builtin_amdgcn_mfma_f32_16x16x32_bf16(p2, av, acc, 0, 0, 0);
            }
        }
    }
    // epilogue -> sRed, capture d into sD
    int gi = b * NN + i0 + m16;
    float d = rsqrtf(dsum[lap * (NB * NN) + gi] + 1.0f + 1e-5f);
    if (cg == 0 && quad == 0) sD[lap][m16] = d;
    int cbase = cg * 16 + quad * 4;
#pragma unroll
    for (int r = 0; r < 4; ++r) {
        int c32 = cbase + r;
        int pcol = lap * 64 + ch * 32 + c32;
        size_t pidx = ((size_t)(b * 128 + pcol)) * NN + i0 + m16;
        float pv = bf2f(Pa[pidx]);
        if (dualP) pv += bf2f(Pb[pidx]);
        sRed[lap][c32][m16] = d * (acc[r] + pv);
    }
    __syncthreads();
    // combine laps + bias + mask + relu -> sH16 (block's 16 rows x 32 cols)
#pragma unroll
    for (int s = 0; s < 2; ++s) {
        int idx = t + s * 256;
        int c32 = idx & 31, i = idx >> 5;
        float mv = mask[b * NN + i0 + i];
        float v = (sRed[0][c32][i] + sRed[1][c32][i] + gb[ch * 32 + c32]) * mv;
        sH16[i][c32] = fmaxf(v, 0.f);
    }
    __syncthreads();

    if (mode == 0) {
        // ---- phase B: partial pre for next layer via MFMA, K=32 (block's cols)
        // stage sWT[c][k] = bf16(gwN[(c<64 ? ch*32+k : 64+ch*32+k)][c&63])
#pragma unroll
        for (int kk = 0; kk < 8; ++kk) {
            int chunk = t + kk * 256;            // 0..2047
            int c = chunk & 127;
            int k = (chunk >> 7) * 2;            // even k
            int base = (c < 64) ? (ch * 32) : (64 + ch * 32);
            int gc = c & 63;
            float f0 = gwN[(size_t)(base + k) * 64 + gc];
            float f1 = gwN[(size_t)(base + k + 1) * 64 + gc];
            unsigned pk = (unsigned)f2bf(f0) | ((unsigned)f2bf(f1) << 16);
            *(unsigned*)&u.b.sWT[c][k] = pk;
        }
        __syncthreads();
        // B-frag: h^T — lane: i=m16, k=quad*8+j from sH16[m16][...]
        float4 h0 = *(const float4*)&sH16[m16][quad * 8];
        float4 h1 = *(const float4*)&sH16[m16][quad * 8 + 4];
        short8 bf;
        bf[0] = f2bf(h0.x); bf[1] = f2bf(h0.y); bf[2] = f2bf(h0.z); bf[3] = f2bf(h0.w);
        bf[4] = f2bf(h1.x); bf[5] = f2bf(h1.y); bf[6] = f2bf(h1.z); bf[7] = f2bf(h1.w);
        ushort_t* Q = ch ? Qb : Qa;
#pragma unroll
        for (int s2 = 0; s2 < 2; ++s2) {
            int ctile = w * 2 + s2;              // 0..7
            short8 af = *(const short8*)&u.b.sWT[ctile * 16 + m16][quad * 8];
            float4v dacc = {0.f, 0.f, 0.f, 0.f};
            dacc = __builtin_amdgcn_mfma_f32_16x16x32_bf16(af, bf, dacc, 0, 0, 0);
            // D[m=c][n=i]: lane n=i=m16; c = ctile*16 + quad*4 + r
            float dsc = sD[(ctile >= 4) ? 1 : 0][m16];
#pragma unroll
            for (int r = 0; r < 4; ++r) {
                int c = ctile * 16 + quad * 4 + r;
                Q[((size_t)(b * 128 + c)) * NN + i0 + m16] = f2bf(dsc * dacc[r]);
            }
        }
    } else {
        // ---- phase C: max-pool + FC
        if (t < 32) {
            float mx = 0.f;
#pragma unroll
            for (int r = 0; r < 16; ++r) mx = fmaxf(mx, sH16[r][t]);
            atomicMax(&gmax[b * 64 + ch * 32 + t], __float_as_uint(mx));
        }
        __syncthreads();
        if (t == 0) {
            __threadfence();
            int old = atomicAdd(&done[b], 1);
            lastFlag = (old == 63);
        }
        __syncthreads();
        if (lastFlag) {
            if (t < 64) {
                unsigned ub = __hip_atomic_load(&gmax[b * 64 + t],
                                                __ATOMIC_RELAXED,
                                                __HIP_MEMORY_SCOPE_AGENT);
                ((float*)sRed)[t] = __uint_as_float(ub);
            }
            __syncthreads();
            if (t < 2) {
                float a2 = fcb[t];
#pragma unroll
                for (int k = 0; k < 64; ++k)
                    a2 = fmaf(((float*)sRed)[k], fcw[k * 2 + t], a2);
                out[b * 2 + t] = a2;
            }
        }
    }
}

extern "C" void kernel_launch(void* const* d_in, const int* in_sizes, int n_in,
                              void* d_out, int out_size, void* d_ws, size_t ws_size,
                              hipStream_t stream)
{
    const float* x    = (const float*)d_in[0];
    const float* A    = (const float*)d_in[1];
    const float* mask = (const float*)d_in[2];
    const float* ew1  = (const float*)d_in[3];
    const float* eb1  = (const float*)d_in[4];
    const float* ew2  = (const float*)d_in[5];
    const float* eb2  = (const float*)d_in[6];
    const float* gw0  = (const float*)d_in[7];
    const float* gb0  = (const float*)d_in[8];
    const float* gw1  = (const float*)d_in[9];
    const float* gb1  = (const float*)d_in[10];
    const float* gw2  = (const float*)d_in[11];
    const float* gb2  = (const float*)d_in[12];
    const float* fcw  = (const float*)d_in[13];
    const float* fcb  = (const float*)d_in[14];
    float* out = (float*)d_out;
    char* ws = (char*)d_ws;

    const size_t NEL = (size_t)NB * NN * NN;      // 2,097,152
    const size_t PSL = (size_t)NB * 128 * NN;     // 524,288 (one P slice)
    float*    xab  = (float*)ws;                   ws += 262144 * 4;
    ushort_t* APh  = (ushort_t*)ws;                ws += NEL * 2;
    ushort_t* Ahs  = (ushort_t*)ws;                ws += NEL * 2;
    float*    dsum = (float*)ws;                   ws += 8192 * 4;
    ushort_t* PT_A = (ushort_t*)ws;                ws += PSL * 2;
    ushort_t* PB1a = (ushort_t*)ws;                ws += PSL * 2;
    ushort_t* PB1b = (ushort_t*)ws;                ws += PSL * 2;
    ushort_t* PB2a = (ushort_t*)ws;                ws += PSL * 2;
    ushort_t* PB2b = (ushort_t*)ws;                ws += PSL * 2;
    unsigned* gmax = (unsigned*)ws;                ws += 512 * 4;
    int*      done = (int*)ws;                     ws += 64 * 4;
    // total ~15 MB

    xaxb_gemm  <<<256, 256, 0, stream>>>(x, ew1, eb1, xab, dsum, gmax, done);
    edge_scores<<<dim3(136, 1, NB), 256, 0, stream>>>(xab, ew2, eb2, mask,
                                                      A, Ahs, APh, dsum);
    pre_gemmT  <<<256, 256, 0, stream>>>(x, gw0, dsum, PT_A, 256);

    // layer 0: single-P (PT_A), emits PB1 slices for layer 1
    fused_layer<<<dim3(32, 2, NB), 256, 0, stream>>>(
        Ahs, APh, PT_A, PT_A, PB1a, PB1b, dsum, gb0, mask, gw1,
        gmax, done, fcw, fcb, out, 0, 0);
    // layer 1: dual-P (PB1), emits PB2 slices for layer 2
    fused_layer<<<dim3(32, 2, NB), 256, 0, stream>>>(
        Ahs, APh, PB1a, PB1b, PB2a, PB2b, dsum, gb1, mask, gw2,
        gmax, done, fcw, fcb, out, 1, 0);
    // layer 2: dual-P (PB2), final max-pool + FC
    fused_layer<<<dim3(32, 2, NB), 256, 0, stream>>>(
        Ahs, APh, PB2a, PB2b, PB2a, PB2b, dsum, gb2, mask, gw2,
        gmax, done, fcw, fcb, out, 1, 1);
}